// Round 2
// baseline (324.411 us; speedup 1.0000x reference)
//
#include <hip/hip_runtime.h>
#include <cstdint>
#include <cmath>

// Problem constants
#define NB 2
#define NC 256
#define HW 2304          // 48*48
#define HID 64
#define OH 96
#define OW 96
#define N1 9216          // 96*96
#define SCALE_ATTN 0.17677669529663689f   // 32^-0.5
#define INV_SCALE 5.65685424949238f       // sqrt(32)
#define RESZ ((float)(47.0/95.0))

// ---------------- K0: transpose Wq/Wk into [c][128] (t<64 -> Wq row t, else Wk row t-64)
__global__ void k0_wt(const float* __restrict__ Wq, const float* __restrict__ Wk,
                      float* __restrict__ WT) {
    int idx = blockIdx.x * 256 + threadIdx.x;   // 256*128
    if (idx >= 256 * 128) return;
    int c = idx >> 7, t = idx & 127;
    WT[idx] = (t < 64) ? Wq[t * 256 + c] : Wk[(t - 64) * 256 + c];
}

// ---------------- K1: channel LN over 256 + Q/K projection. 1 block per pixel, 128 thr.
// q written pixel-major: q_pix[b][p48][64]; k written NHWC per group: k_nhwc[bg][p48][32]
__global__ void k1_ln_qk(const float* __restrict__ x, const float* __restrict__ ln_g,
                         const float* __restrict__ ln_b, const float* __restrict__ WT,
                         float* __restrict__ q_pix, float* __restrict__ k_nhwc) {
    int blk = blockIdx.x;                 // 0..4607
    int b = blk / HW, p = blk % HW;
    int tid = threadIdx.x;                // 0..127
    __shared__ float xs[256];
    __shared__ float red[128];
    const float* xb = x + (size_t)b * NC * HW + p;
    float v0 = xb[(size_t)tid * HW];
    float v1 = xb[(size_t)(tid + 128) * HW];
    red[tid] = v0 + v1;
    __syncthreads();
    for (int off = 64; off > 0; off >>= 1) {
        if (tid < off) red[tid] += red[tid + off];
        __syncthreads();
    }
    float mu = red[0] * (1.f / 256.f);
    __syncthreads();
    float d0 = v0 - mu, d1 = v1 - mu;
    red[tid] = d0 * d0 + d1 * d1;
    __syncthreads();
    for (int off = 64; off > 0; off >>= 1) {
        if (tid < off) red[tid] += red[tid + off];
        __syncthreads();
    }
    float rs = rsqrtf(red[0] * (1.f / 256.f) + 1e-5f);
    __syncthreads();
    xs[tid]       = d0 * rs * ln_g[tid] + ln_b[tid];
    xs[tid + 128] = d1 * rs * ln_g[tid + 128] + ln_b[tid + 128];
    __syncthreads();
    float acc = 0.f;
#pragma unroll 8
    for (int c = 0; c < 256; c++) acc += WT[c * 128 + tid] * xs[c];
    if (tid < 64) {
        q_pix[((size_t)b * HW + p) * 64 + tid] = acc;
    } else {
        int t = tid - 64, g = t >> 5, c32 = t & 31;
        k_nhwc[(((size_t)(b * 2 + g) * HW) + p) * 32 + c32] = acc;
    }
}

// ---------------- K2: bilinear resize q 48->96 (align_corners), pixel-major in and out.
// q_attn[b][p96][64] = resized * SCALE_ATTN
__global__ void k2_resize(const float* __restrict__ q_pix, float* __restrict__ q_attn) {
    int idx = blockIdx.x * 256 + threadIdx.x;   // 2*9216*64
    if (idx >= NB * N1 * HID) return;
    int c = idx & 63;
    int t = idx >> 6;
    int p = t % N1;
    int b = t / N1;
    int oy = p / OW, ox = p % OW;
    float ys = oy * RESZ, xsf = ox * RESZ;
    int y0 = (int)floorf(ys); y0 = min(max(y0, 0), 46); float wy = ys - (float)y0;
    int x0 = (int)floorf(xsf); x0 = min(max(x0, 0), 46); float wx = xsf - (float)x0;
    const float* base = q_pix + (size_t)b * HW * 64 + c;
    float a00 = base[(y0 * 48 + x0) * 64],       a01 = base[(y0 * 48 + x0 + 1) * 64];
    float a10 = base[((y0 + 1) * 48 + x0) * 64], a11 = base[((y0 + 1) * 48 + x0 + 1) * 64];
    float v = (a00 * (1.f - wy) + a10 * wy) * (1.f - wx) + (a01 * (1.f - wy) + a11 * wy) * wx;
    q_attn[idx] = v * SCALE_ATTN;
}

// ---------------- K2b: v (=x) NCHW -> NHWC per group: [4][2304][128]
__global__ void k2b_vt(const float* __restrict__ x, float* __restrict__ v_nhwc) {
    int idx = blockIdx.x * 256 + threadIdx.x;   // 4*2304*128
    if (idx >= 4 * HW * 128) return;
    int c = idx & 127;
    int t = idx >> 7;
    int p = t % HW;
    int bg = t / HW;
    int b = bg >> 1, g = bg & 1;
    v_nhwc[idx] = x[((size_t)(b * NC + g * 128 + c)) * HW + p];
}

// ---------------- K34: fused depthwise3x3 + LN(32) + GELU + conv3x3(32->18)+bias.
// grid: 4 bg * 36 tiles (16x16). LDS holds 18x18 halo of the intermediate t.
__global__ __launch_bounds__(256) void k34_off(const float* __restrict__ q_attn,
                                               const float* __restrict__ dw_w,
                                               const float* __restrict__ og,
                                               const float* __restrict__ ob,
                                               const float* __restrict__ off_w,
                                               const float* __restrict__ off_b,
                                               float* __restrict__ pred) {
    int blk = blockIdx.x;
    int bg = blk / 36, tile = blk % 36;
    int ty0 = (tile / 6) * 16, tx0 = (tile % 6) * 16;
    int b = bg >> 1, g = bg & 1;
    int tid = threadIdx.x;
    __shared__ float ts[324][33];   // 18x18 halo x 32ch (+1 pad)

    for (int hp = tid; hp < 324; hp += 256) {
        int hy = ty0 + hp / 18 - 1;
        int hx = tx0 + hp % 18 - 1;
        if (hy < 0 || hy >= OH || hx < 0 || hx >= OW) {
#pragma unroll
            for (int c = 0; c < 32; c++) ts[hp][c] = 0.f;
        } else {
            float vals[32];
#pragma unroll
            for (int c = 0; c < 32; c++) vals[c] = 0.f;
            for (int dy = -1; dy <= 1; dy++) {
                int yy = hy + dy;
                if ((unsigned)yy >= (unsigned)OH) continue;
                for (int dx = -1; dx <= 1; dx++) {
                    int xx = hx + dx;
                    if ((unsigned)xx >= (unsigned)OW) continue;
                    const float4* qp4 = (const float4*)(q_attn +
                        (((size_t)b * N1) + yy * OW + xx) * 64 + g * 32);
                    int wi = (dy + 1) * 3 + (dx + 1);
#pragma unroll
                    for (int c4 = 0; c4 < 8; c4++) {
                        float4 q4 = qp4[c4];
                        vals[c4 * 4 + 0] += q4.x * dw_w[(c4 * 4 + 0) * 9 + wi];
                        vals[c4 * 4 + 1] += q4.y * dw_w[(c4 * 4 + 1) * 9 + wi];
                        vals[c4 * 4 + 2] += q4.z * dw_w[(c4 * 4 + 2) * 9 + wi];
                        vals[c4 * 4 + 3] += q4.w * dw_w[(c4 * 4 + 3) * 9 + wi];
                    }
                }
            }
            float sum = 0.f;
#pragma unroll
            for (int c = 0; c < 32; c++) { vals[c] *= INV_SCALE; sum += vals[c]; }
            float mu = sum * (1.f / 32.f);
            float var = 0.f;
#pragma unroll
            for (int c = 0; c < 32; c++) { float d = vals[c] - mu; var += d * d; }
            float rsv = rsqrtf(var * (1.f / 32.f) + 1e-5f);
#pragma unroll
            for (int c = 0; c < 32; c++) {
                float v = (vals[c] - mu) * rsv * og[c] + ob[c];
                ts[hp][c] = 0.5f * v * (1.f + erff(v * 0.70710678118654752f));
            }
        }
    }
    __syncthreads();

    int oyl = tid >> 4, oxl = tid & 15;
    int p = (ty0 + oyl) * OW + tx0 + oxl;
    for (int oc = 0; oc < 18; oc++) {
        float acc = off_b[oc];
        const float* wb = off_w + oc * 288;
        for (int ic = 0; ic < 32; ic++) {
            const float* wc = wb + ic * 9;
#pragma unroll
            for (int dy = 0; dy < 3; dy++) {
#pragma unroll
                for (int dx = 0; dx < 3; dx++) {
                    acc += ts[(oyl + dy) * 18 + oxl + dx][ic] * wc[dy * 3 + dx];
                }
            }
        }
        pred[((size_t)bg * 18 + oc) * N1 + p] = acc;
    }
}

// bilinear sample with zeros padding, unnormalized input coords, NHWC base
__device__ __forceinline__ float bsamp(const float* __restrict__ base, float iy, float ix,
                                       int sc, int c) {
    float y0f = floorf(iy), x0f = floorf(ix);
    float wy = iy - y0f, wx = ix - x0f;
    int y0 = (int)y0f, x0 = (int)x0f;
    int y1 = y0 + 1, x1 = x0 + 1;
    bool vy0 = (unsigned)y0 < 48u, vy1 = (unsigned)y1 < 48u;
    bool vx0 = (unsigned)x0 < 48u, vx1 = (unsigned)x1 < 48u;
    int y0c = min(max(y0, 0), 47), y1c = min(max(y1, 0), 47);
    int x0c = min(max(x0, 0), 47), x1c = min(max(x1, 0), 47);
    float a00 = (vy0 && vx0) ? base[(y0c * 48 + x0c) * sc + c] : 0.f;
    float a01 = (vy0 && vx1) ? base[(y0c * 48 + x1c) * sc + c] : 0.f;
    float a10 = (vy1 && vx0) ? base[(y1c * 48 + x0c) * sc + c] : 0.f;
    float a11 = (vy1 && vx1) ? base[(y1c * 48 + x1c) * sc + c] : 0.f;
    return (a00 * (1.f - wy) + a10 * wy) * (1.f - wx) + (a01 * (1.f - wy) + a11 * wy) * wx;
}

// ---------------- K5: deformable attention. 1 wave per (bg, pixel); 4 waves/block (same bg, p..p+3).
__global__ __launch_bounds__(256) void k5_attn(const float* __restrict__ pred,
                                               const float* __restrict__ q_attn,
                                               const float* __restrict__ k_nhwc,
                                               const float* __restrict__ v_nhwc,
                                               const float* __restrict__ rpb,
                                               float* __restrict__ out) {
    int tid = threadIdx.x;
    int wv = tid >> 6, lane = tid & 63;
    int gw = blockIdx.x * 4 + wv;          // 0..36863
    int bg = gw / N1, p = gw % N1;
    int b = bg >> 1, g = bg & 1;
    int oy = p / OW, ox = p % OW;

    __shared__ float siy[4][9], six[4][9], ss[4][12];
    __shared__ float outb[128][5];

    if (lane < 9) {
        int j = lane, ky = j / 3, kx = j % 3;
        float py = tanhf(pred[((size_t)bg * 18 + j * 2) * N1 + p]) * 11.0f + (float)(ky - 1) + (float)oy;
        float px = tanhf(pred[((size_t)bg * 18 + j * 2 + 1) * N1 + p]) * 11.0f + (float)(kx - 1) + (float)ox;
        siy[wv][j] = py * RESZ;
        six[wv][j] = px * RESZ;
    }
    __syncthreads();

    int c = lane & 31, h = lane >> 5;
    float qv = q_attn[((size_t)b * N1 + p) * HID + g * 32 + c];
    const float* kb = k_nhwc + (size_t)bg * HW * 32;

    for (int jj = 0; jj < 5; jj++) {
        int j = jj * 2 + h;
        float partial = 0.f;
        if (j < 9) {
            float kv = bsamp(kb, siy[wv][j], six[wv][j], 32, c);
            partial = qv * (kv + rpb[((size_t)g * 9 + j) * 32 + c]);
        }
#pragma unroll
        for (int off = 1; off < 32; off <<= 1) partial += __shfl_xor(partial, off);
        if (c == 0 && j < 9) ss[wv][j] = partial;
    }
    __syncthreads();

    float sc[9];
    float m = -1e30f;
#pragma unroll
    for (int j = 0; j < 9; j++) { sc[j] = ss[wv][j]; m = fmaxf(m, sc[j]); }
    float sum = 0.f;
#pragma unroll
    for (int j = 0; j < 9; j++) { sc[j] = expf(sc[j] - m); sum += sc[j]; }
    float inv = 1.f / sum;

    const float* vb = v_nhwc + (size_t)bg * HW * 128;
#pragma unroll
    for (int it = 0; it < 2; it++) {
        int cc = it * 64 + lane;
        float acc = 0.f;
#pragma unroll
        for (int j = 0; j < 9; j++) {
            float sv = bsamp(vb, siy[wv][j], six[wv][j], 128, cc);
            acc += (sc[j] * inv) * sv;
        }
        outb[cc][wv] = acc;
    }
    __syncthreads();

    // transposed write: thread t<128 writes float4 (4 consecutive pixels) for channel t
    if (tid < 128) {
        int bg0 = (blockIdx.x * 4) / N1;
        int p0 = (blockIdx.x * 4) % N1;
        int b0 = bg0 >> 1, g0 = bg0 & 1;
        float4 v4 = make_float4(outb[tid][0], outb[tid][1], outb[tid][2], outb[tid][3]);
        *(float4*)(out + ((size_t)b0 * NC + g0 * 128 + tid) * N1 + p0) = v4;
    }
}

extern "C" void kernel_launch(void* const* d_in, const int* in_sizes, int n_in,
                              void* d_out, int out_size, void* d_ws, size_t ws_size,
                              hipStream_t stream) {
    const float* x      = (const float*)d_in[0];
    const float* ln_g   = (const float*)d_in[1];
    const float* ln_b   = (const float*)d_in[2];
    const float* Wq     = (const float*)d_in[3];
    const float* Wk     = (const float*)d_in[4];
    const float* dw_w   = (const float*)d_in[5];
    const float* off_g  = (const float*)d_in[6];
    const float* off_bt = (const float*)d_in[7];
    const float* off_w  = (const float*)d_in[8];
    const float* off_b  = (const float*)d_in[9];
    const float* rpb    = (const float*)d_in[10];
    float* out = (float*)d_out;

    // Workspace layout (floats). Total = 3,350,528 floats = 12.8 MB.
    // Region R is time-shared: q_pix (k1->k2) then pred (k34->k5).
    float* ws = (float*)d_ws;
    float* WT     = ws;                       // 32768
    float* k_nhwc = WT + 32768;               // 294912  [4][2304][32]
    float* v_nhwc = k_nhwc + 294912;          // 1179648 [4][2304][128]
    float* q_attn = v_nhwc + 1179648;         // 1179648 [2][9216][64] (scaled)
    float* R      = q_attn + 1179648;         // 663552
    float* q_pix  = R;                        // 294912  [2][2304][64]
    float* pred   = R;                        // 663552  [4][18][9216]

    k0_wt<<<128, 256, 0, stream>>>(Wq, Wk, WT);
    k1_ln_qk<<<NB * HW, 128, 0, stream>>>(x, ln_g, ln_b, WT, q_pix, k_nhwc);
    k2b_vt<<<4608, 256, 0, stream>>>(x, v_nhwc);
    k2_resize<<<4608, 256, 0, stream>>>(q_pix, q_attn);
    k34_off<<<144, 256, 0, stream>>>(q_attn, dw_w, off_g, off_bt, off_w, off_b, pred);
    k5_attn<<<9216, 256, 0, stream>>>(pred, q_attn, k_nhwc, v_nhwc, rpb, out);
}

// Round 3
// 246.208 us; speedup vs baseline: 1.3176x; 1.3176x over previous
//
#include <hip/hip_runtime.h>
#include <cstdint>
#include <cmath>

// Problem constants
#define NB 2
#define NC 256
#define HW 2304          // 48*48
#define HID 64
#define OH 96
#define OW 96
#define N1 9216          // 96*96
#define SCALE_ATTN 0.17677669529663689f   // 32^-0.5
#define INV_SCALE 5.65685424949238f       // sqrt(32)
#define RESZ ((float)(47.0/95.0))

// ---------------- K0: transpose Wq/Wk into [c][128]; also off_w -> wT2[k=ic*9+tap][18 oc]
__global__ void k0_wt(const float* __restrict__ Wq, const float* __restrict__ Wk,
                      const float* __restrict__ off_w,
                      float* __restrict__ WT, float* __restrict__ wT2) {
    int idx = blockIdx.x * 256 + threadIdx.x;
    if (idx < 256 * 128) {
        int c = idx >> 7, t = idx & 127;
        WT[idx] = (t < 64) ? Wq[t * 256 + c] : Wk[(t - 64) * 256 + c];
    } else if (idx < 256 * 128 + 288 * 18) {
        int i = idx - 256 * 128;
        int k = i / 18, oc = i % 18;
        wT2[i] = off_w[oc * 288 + k];
    }
}

// ---------------- K1: channel LN over 256 + Q/K projection. 1 block per pixel, 128 thr.
// q written pixel-major: q_pix[b][p48][64]; k written NHWC per group: k_nhwc[bg][p48][32]
__global__ void k1_ln_qk(const float* __restrict__ x, const float* __restrict__ ln_g,
                         const float* __restrict__ ln_b, const float* __restrict__ WT,
                         float* __restrict__ q_pix, float* __restrict__ k_nhwc) {
    int blk = blockIdx.x;                 // 0..4607
    int b = blk / HW, p = blk % HW;
    int tid = threadIdx.x;                // 0..127
    __shared__ float xs[256];
    __shared__ float red[128];
    const float* xb = x + (size_t)b * NC * HW + p;
    float v0 = xb[(size_t)tid * HW];
    float v1 = xb[(size_t)(tid + 128) * HW];
    red[tid] = v0 + v1;
    __syncthreads();
    for (int off = 64; off > 0; off >>= 1) {
        if (tid < off) red[tid] += red[tid + off];
        __syncthreads();
    }
    float mu = red[0] * (1.f / 256.f);
    __syncthreads();
    float d0 = v0 - mu, d1 = v1 - mu;
    red[tid] = d0 * d0 + d1 * d1;
    __syncthreads();
    for (int off = 64; off > 0; off >>= 1) {
        if (tid < off) red[tid] += red[tid + off];
        __syncthreads();
    }
    float rs = rsqrtf(red[0] * (1.f / 256.f) + 1e-5f);
    __syncthreads();
    xs[tid]       = d0 * rs * ln_g[tid] + ln_b[tid];
    xs[tid + 128] = d1 * rs * ln_g[tid + 128] + ln_b[tid + 128];
    __syncthreads();
    float acc = 0.f;
#pragma unroll 8
    for (int c = 0; c < 256; c++) acc += WT[c * 128 + tid] * xs[c];
    if (tid < 64) {
        q_pix[((size_t)b * HW + p) * 64 + tid] = acc;
    } else {
        int t = tid - 64, g = t >> 5, c32 = t & 31;
        k_nhwc[(((size_t)(b * 2 + g) * HW) + p) * 32 + c32] = acc;
    }
}

// ---------------- K2: bilinear resize q 48->96 (align_corners), pixel-major in and out.
__global__ void k2_resize(const float* __restrict__ q_pix, float* __restrict__ q_attn) {
    int idx = blockIdx.x * 256 + threadIdx.x;   // 2*9216*64
    if (idx >= NB * N1 * HID) return;
    int c = idx & 63;
    int t = idx >> 6;
    int p = t % N1;
    int b = t / N1;
    int oy = p / OW, ox = p % OW;
    float ys = oy * RESZ, xsf = ox * RESZ;
    int y0 = (int)floorf(ys); y0 = min(max(y0, 0), 46); float wy = ys - (float)y0;
    int x0 = (int)floorf(xsf); x0 = min(max(x0, 0), 46); float wx = xsf - (float)x0;
    const float* base = q_pix + (size_t)b * HW * 64 + c;
    float a00 = base[(y0 * 48 + x0) * 64],       a01 = base[(y0 * 48 + x0 + 1) * 64];
    float a10 = base[((y0 + 1) * 48 + x0) * 64], a11 = base[((y0 + 1) * 48 + x0 + 1) * 64];
    float v = (a00 * (1.f - wy) + a10 * wy) * (1.f - wx) + (a01 * (1.f - wy) + a11 * wy) * wx;
    q_attn[idx] = v * SCALE_ATTN;
}

// ---------------- K2b: v (=x) NCHW -> NHWC per group via LDS tile: [4][2304][128]
__global__ void k2b_vt(const float* __restrict__ x, float* __restrict__ v_nhwc) {
    // grid: bg(4) x ctile(4) x ptile(72); block 256 (8 rows of 32)
    int blk = blockIdx.x;
    int pt = blk % 72;
    int t2 = blk / 72;
    int ct = t2 & 3;
    int bg = t2 >> 2;
    int b = bg >> 1, g = bg & 1;
    __shared__ float tile[32][33];
    int tx = threadIdx.x & 31, row = threadIdx.x >> 5;   // row 0..7
#pragma unroll
    for (int r = 0; r < 4; r++) {
        int c = ct * 32 + row + r * 8;
        tile[row + r * 8][tx] = x[((size_t)(b * 256 + g * 128 + c)) * HW + pt * 32 + tx];
    }
    __syncthreads();
#pragma unroll
    for (int r = 0; r < 4; r++) {
        int p = pt * 32 + row + r * 8;
        v_nhwc[((size_t)bg * HW + p) * 128 + ct * 32 + tx] = tile[tx][row + r * 8];
    }
}

// ---------------- K34: fused depthwise3x3 + LN(32) + GELU + conv3x3(32->18)+bias.
// grid: 4 bg * 72 tiles (16x8). Phase1: 180-point halo of t in LDS.
// Phase2: thread-per-pixel, 9 oc per thread (waves 0-1: oc0-8, waves 2-3: oc9-17),
// weights read via wave-uniform address from pre-transposed wT2 -> scalar loads.
__global__ __launch_bounds__(256) void k34_off(const float* __restrict__ q_attn,
                                               const float* __restrict__ dw_w,
                                               const float* __restrict__ og,
                                               const float* __restrict__ ob,
                                               const float* __restrict__ wT2,
                                               const float* __restrict__ off_b,
                                               float* __restrict__ pred) {
    int blk = blockIdx.x;
    int bg = blk / 72, tile = blk % 72;
    int ty0 = (tile / 6) * 8, tx0 = (tile % 6) * 16;
    int b = bg >> 1, g = bg & 1;
    int tid = threadIdx.x;
    __shared__ float ts[180][33];   // 18(w) x 10(h) halo x 32ch (+1 pad)

    if (tid < 180) {
        int hy = ty0 + tid / 18 - 1;
        int hx = tx0 + tid % 18 - 1;
        if (hy < 0 || hy >= OH || hx < 0 || hx >= OW) {
#pragma unroll
            for (int c = 0; c < 32; c++) ts[tid][c] = 0.f;
        } else {
            float vals[32];
#pragma unroll
            for (int c = 0; c < 32; c++) vals[c] = 0.f;
            for (int dy = -1; dy <= 1; dy++) {
                int yy = hy + dy;
                if ((unsigned)yy >= (unsigned)OH) continue;
                for (int dx = -1; dx <= 1; dx++) {
                    int xx = hx + dx;
                    if ((unsigned)xx >= (unsigned)OW) continue;
                    const float4* qp4 = (const float4*)(q_attn +
                        (((size_t)b * N1) + yy * OW + xx) * 64 + g * 32);
                    int wi = (dy + 1) * 3 + (dx + 1);
#pragma unroll
                    for (int c4 = 0; c4 < 8; c4++) {
                        float4 q4 = qp4[c4];
                        vals[c4 * 4 + 0] += q4.x * dw_w[(c4 * 4 + 0) * 9 + wi];
                        vals[c4 * 4 + 1] += q4.y * dw_w[(c4 * 4 + 1) * 9 + wi];
                        vals[c4 * 4 + 2] += q4.z * dw_w[(c4 * 4 + 2) * 9 + wi];
                        vals[c4 * 4 + 3] += q4.w * dw_w[(c4 * 4 + 3) * 9 + wi];
                    }
                }
            }
            float sum = 0.f;
#pragma unroll
            for (int c = 0; c < 32; c++) { vals[c] *= INV_SCALE; sum += vals[c]; }
            float mu = sum * (1.f / 32.f);
            float var = 0.f;
#pragma unroll
            for (int c = 0; c < 32; c++) { float d = vals[c] - mu; var += d * d; }
            float rsv = rsqrtf(var * (1.f / 32.f) + 1e-5f);
#pragma unroll
            for (int c = 0; c < 32; c++) {
                float v = (vals[c] - mu) * rsv * og[c] + ob[c];
                ts[tid][c] = 0.5f * v * (1.f + erff(v * 0.70710678118654752f));
            }
        }
    }
    __syncthreads();

    // Phase 2
    int och = __builtin_amdgcn_readfirstlane(tid >> 7) * 9;   // wave-uniform
    int pixL = tid & 127;
    int oyl = pixL >> 4, oxl = pixL & 15;
    float acc[9];
#pragma unroll
    for (int o = 0; o < 9; o++) acc[o] = off_b[och + o];
    for (int ic = 0; ic < 32; ic++) {
#pragma unroll
        for (int dy = 0; dy < 3; dy++) {
#pragma unroll
            for (int dx = 0; dx < 3; dx++) {
                float tv = ts[(oyl + dy) * 18 + oxl + dx][ic];
                const float* wr = wT2 + (ic * 9 + dy * 3 + dx) * 18 + och;
#pragma unroll
                for (int o = 0; o < 9; o++) acc[o] += tv * wr[o];
            }
        }
    }
    int p = (ty0 + oyl) * OW + tx0 + oxl;
#pragma unroll
    for (int o = 0; o < 9; o++)
        pred[((size_t)bg * 18 + och + o) * N1 + p] = acc[o];
}

// bilinear sample with zeros padding, unnormalized input coords, NHWC base
__device__ __forceinline__ float bsamp(const float* __restrict__ base, float iy, float ix,
                                       int sc, int c) {
    float y0f = floorf(iy), x0f = floorf(ix);
    float wy = iy - y0f, wx = ix - x0f;
    int y0 = (int)y0f, x0 = (int)x0f;
    int y1 = y0 + 1, x1 = x0 + 1;
    bool vy0 = (unsigned)y0 < 48u, vy1 = (unsigned)y1 < 48u;
    bool vx0 = (unsigned)x0 < 48u, vx1 = (unsigned)x1 < 48u;
    int y0c = min(max(y0, 0), 47), y1c = min(max(y1, 0), 47);
    int x0c = min(max(x0, 0), 47), x1c = min(max(x1, 0), 47);
    float a00 = (vy0 && vx0) ? base[(y0c * 48 + x0c) * sc + c] : 0.f;
    float a01 = (vy0 && vx1) ? base[(y0c * 48 + x1c) * sc + c] : 0.f;
    float a10 = (vy1 && vx0) ? base[(y1c * 48 + x0c) * sc + c] : 0.f;
    float a11 = (vy1 && vx1) ? base[(y1c * 48 + x1c) * sc + c] : 0.f;
    return (a00 * (1.f - wy) + a10 * wy) * (1.f - wx) + (a01 * (1.f - wy) + a11 * wy) * wx;
}

// ---------------- K5: deformable attention. 1 wave per (bg, pixel); 4 waves/block.
__global__ __launch_bounds__(256) void k5_attn(const float* __restrict__ pred,
                                               const float* __restrict__ q_attn,
                                               const float* __restrict__ k_nhwc,
                                               const float* __restrict__ v_nhwc,
                                               const float* __restrict__ rpb,
                                               float* __restrict__ out) {
    int tid = threadIdx.x;
    int wv = tid >> 6, lane = tid & 63;
    int gw = blockIdx.x * 4 + wv;          // 0..36863
    int bg = gw / N1, p = gw % N1;
    int b = bg >> 1, g = bg & 1;
    int oy = p / OW, ox = p % OW;

    __shared__ float siy[4][9], six[4][9], ss[4][12];
    __shared__ float outb[128][5];

    if (lane < 9) {
        int j = lane, ky = j / 3, kx = j % 3;
        float py = tanhf(pred[((size_t)bg * 18 + j * 2) * N1 + p]) * 11.0f + (float)(ky - 1) + (float)oy;
        float px = tanhf(pred[((size_t)bg * 18 + j * 2 + 1) * N1 + p]) * 11.0f + (float)(kx - 1) + (float)ox;
        siy[wv][j] = py * RESZ;
        six[wv][j] = px * RESZ;
    }
    __syncthreads();

    int c = lane & 31, h = lane >> 5;
    float qv = q_attn[((size_t)b * N1 + p) * HID + g * 32 + c];
    const float* kb = k_nhwc + (size_t)bg * HW * 32;

    for (int jj = 0; jj < 5; jj++) {
        int j = jj * 2 + h;
        float partial = 0.f;
        if (j < 9) {
            float kv = bsamp(kb, siy[wv][j], six[wv][j], 32, c);
            partial = qv * (kv + rpb[((size_t)g * 9 + j) * 32 + c]);
        }
#pragma unroll
        for (int off = 1; off < 32; off <<= 1) partial += __shfl_xor(partial, off);
        if (c == 0 && j < 9) ss[wv][j] = partial;
    }
    __syncthreads();

    float sc[9];
    float m = -1e30f;
#pragma unroll
    for (int j = 0; j < 9; j++) { sc[j] = ss[wv][j]; m = fmaxf(m, sc[j]); }
    float sum = 0.f;
#pragma unroll
    for (int j = 0; j < 9; j++) { sc[j] = expf(sc[j] - m); sum += sc[j]; }
    float inv = 1.f / sum;

    const float* vb = v_nhwc + (size_t)bg * HW * 128;
#pragma unroll
    for (int it = 0; it < 2; it++) {
        int cc = it * 64 + lane;
        float acc = 0.f;
#pragma unroll
        for (int j = 0; j < 9; j++) {
            float sv = bsamp(vb, siy[wv][j], six[wv][j], 128, cc);
            acc += (sc[j] * inv) * sv;
        }
        outb[cc][wv] = acc;
    }
    __syncthreads();

    if (tid < 128) {
        int bg0 = (blockIdx.x * 4) / N1;
        int p0 = (blockIdx.x * 4) % N1;
        int b0 = bg0 >> 1, g0 = bg0 & 1;
        float4 v4 = make_float4(outb[tid][0], outb[tid][1], outb[tid][2], outb[tid][3]);
        *(float4*)(out + ((size_t)b0 * NC + g0 * 128 + tid) * N1 + p0) = v4;
    }
}

extern "C" void kernel_launch(void* const* d_in, const int* in_sizes, int n_in,
                              void* d_out, int out_size, void* d_ws, size_t ws_size,
                              hipStream_t stream) {
    const float* x      = (const float*)d_in[0];
    const float* ln_g   = (const float*)d_in[1];
    const float* ln_b   = (const float*)d_in[2];
    const float* Wq     = (const float*)d_in[3];
    const float* Wk     = (const float*)d_in[4];
    const float* dw_w   = (const float*)d_in[5];
    const float* off_g  = (const float*)d_in[6];
    const float* off_bt = (const float*)d_in[7];
    const float* off_w  = (const float*)d_in[8];
    const float* off_b  = (const float*)d_in[9];
    const float* rpb    = (const float*)d_in[10];
    float* out = (float*)d_out;

    // Workspace layout (floats). Total = 3,355,712 floats = 12.80 MB.
    // Region R is time-shared: q_pix (k1->k2) then pred (k34->k5).
    float* ws = (float*)d_ws;
    float* WT     = ws;                       // 32768
    float* k_nhwc = WT + 32768;               // 294912  [4][2304][32]
    float* v_nhwc = k_nhwc + 294912;          // 1179648 [4][2304][128]
    float* q_attn = v_nhwc + 1179648;         // 1179648 [2][9216][64] (scaled)
    float* R      = q_attn + 1179648;         // 663552
    float* q_pix  = R;                        // 294912  [2][2304][64]
    float* pred   = R;                        // 663552  [4][18][9216]
    float* wT2    = R + 663552;               // 5184    [288][18]

    k0_wt<<<149, 256, 0, stream>>>(Wq, Wk, off_w, WT, wT2);
    k1_ln_qk<<<NB * HW, 128, 0, stream>>>(x, ln_g, ln_b, WT, q_pix, k_nhwc);
    k2b_vt<<<1152, 256, 0, stream>>>(x, v_nhwc);
    k2_resize<<<4608, 256, 0, stream>>>(q_pix, q_attn);
    k34_off<<<288, 256, 0, stream>>>(q_attn, dw_w, off_g, off_bt, wT2, off_b, pred);
    k5_attn<<<9216, 256, 0, stream>>>(pred, q_attn, k_nhwc, v_nhwc, rpb, out);
}

// Round 4
// 196.382 us; speedup vs baseline: 1.6519x; 1.2537x over previous
//
#include <hip/hip_runtime.h>
#include <cstdint>
#include <cmath>

// Problem constants
#define NB 2
#define NC 256
#define HW 2304          // 48*48
#define HID 64
#define OH 96
#define OW 96
#define N1 9216          // 96*96
#define SCALE_ATTN 0.17677669529663689f   // 32^-0.5
#define INV_SCALE 5.65685424949238f       // sqrt(32)
#define RESZ ((float)(47.0/95.0))

// ---------------- K0: transpose Wq/Wk into [c][128]; also off_w -> wT2[k=ic*9+tap][18 oc]
__global__ void k0_wt(const float* __restrict__ Wq, const float* __restrict__ Wk,
                      const float* __restrict__ off_w,
                      float* __restrict__ WT, float* __restrict__ wT2) {
    int idx = blockIdx.x * 256 + threadIdx.x;
    if (idx < 256 * 128) {
        int c = idx >> 7, t = idx & 127;
        WT[idx] = (t < 64) ? Wq[t * 256 + c] : Wk[(t - 64) * 256 + c];
    } else if (idx < 256 * 128 + 288 * 18) {
        int i = idx - 256 * 128;
        int k = i / 18, oc = i % 18;
        wT2[i] = off_w[oc * 288 + k];
    }
}

// ---------------- K1: channel LN over 256 + Q/K projection. 1 block per pixel, 128 thr.
__global__ void k1_ln_qk(const float* __restrict__ x, const float* __restrict__ ln_g,
                         const float* __restrict__ ln_b, const float* __restrict__ WT,
                         float* __restrict__ q_pix, float* __restrict__ k_nhwc) {
    int blk = blockIdx.x;                 // 0..4607
    int b = blk / HW, p = blk % HW;
    int tid = threadIdx.x;                // 0..127
    __shared__ float xs[256];
    __shared__ float red[128];
    const float* xb = x + (size_t)b * NC * HW + p;
    float v0 = xb[(size_t)tid * HW];
    float v1 = xb[(size_t)(tid + 128) * HW];
    red[tid] = v0 + v1;
    __syncthreads();
    for (int off = 64; off > 0; off >>= 1) {
        if (tid < off) red[tid] += red[tid + off];
        __syncthreads();
    }
    float mu = red[0] * (1.f / 256.f);
    __syncthreads();
    float d0 = v0 - mu, d1 = v1 - mu;
    red[tid] = d0 * d0 + d1 * d1;
    __syncthreads();
    for (int off = 64; off > 0; off >>= 1) {
        if (tid < off) red[tid] += red[tid + off];
        __syncthreads();
    }
    float rs = rsqrtf(red[0] * (1.f / 256.f) + 1e-5f);
    __syncthreads();
    xs[tid]       = d0 * rs * ln_g[tid] + ln_b[tid];
    xs[tid + 128] = d1 * rs * ln_g[tid + 128] + ln_b[tid + 128];
    __syncthreads();
    float acc = 0.f;
#pragma unroll 8
    for (int c = 0; c < 256; c++) acc += WT[c * 128 + tid] * xs[c];
    if (tid < 64) {
        q_pix[((size_t)b * HW + p) * 64 + tid] = acc;
    } else {
        int t = tid - 64, g = t >> 5, c32 = t & 31;
        k_nhwc[(((size_t)(b * 2 + g) * HW) + p) * 32 + c32] = acc;
    }
}

// ---------------- K2: bilinear resize q 48->96 (align_corners), pixel-major in and out.
__global__ void k2_resize(const float* __restrict__ q_pix, float* __restrict__ q_attn) {
    int idx = blockIdx.x * 256 + threadIdx.x;   // 2*9216*64
    if (idx >= NB * N1 * HID) return;
    int c = idx & 63;
    int t = idx >> 6;
    int p = t % N1;
    int b = t / N1;
    int oy = p / OW, ox = p % OW;
    float ys = oy * RESZ, xsf = ox * RESZ;
    int y0 = (int)floorf(ys); y0 = min(max(y0, 0), 46); float wy = ys - (float)y0;
    int x0 = (int)floorf(xsf); x0 = min(max(x0, 0), 46); float wx = xsf - (float)x0;
    const float* base = q_pix + (size_t)b * HW * 64 + c;
    float a00 = base[(y0 * 48 + x0) * 64],       a01 = base[(y0 * 48 + x0 + 1) * 64];
    float a10 = base[((y0 + 1) * 48 + x0) * 64], a11 = base[((y0 + 1) * 48 + x0 + 1) * 64];
    float v = (a00 * (1.f - wy) + a10 * wy) * (1.f - wx) + (a01 * (1.f - wy) + a11 * wy) * wx;
    q_attn[idx] = v * SCALE_ATTN;
}

// ---------------- K2b: v (=x) NCHW -> NHWC per group via LDS tile: [4][2304][128]
__global__ void k2b_vt(const float* __restrict__ x, float* __restrict__ v_nhwc) {
    int blk = blockIdx.x;
    int pt = blk % 72;
    int t2 = blk / 72;
    int ct = t2 & 3;
    int bg = t2 >> 2;
    int b = bg >> 1, g = bg & 1;
    __shared__ float tile[32][33];
    int tx = threadIdx.x & 31, row = threadIdx.x >> 5;   // row 0..7
#pragma unroll
    for (int r = 0; r < 4; r++) {
        int c = ct * 32 + row + r * 8;
        tile[row + r * 8][tx] = x[((size_t)(b * 256 + g * 128 + c)) * HW + pt * 32 + tx];
    }
    __syncthreads();
#pragma unroll
    for (int r = 0; r < 4; r++) {
        int p = pt * 32 + row + r * 8;
        v_nhwc[((size_t)bg * HW + p) * 128 + ct * 32 + tx] = tile[tx][row + r * 8];
    }
}

// ---------------- K34: fused depthwise3x3 + LN(32) + GELU + conv3x3(32->18)+bias.
__global__ __launch_bounds__(256) void k34_off(const float* __restrict__ q_attn,
                                               const float* __restrict__ dw_w,
                                               const float* __restrict__ og,
                                               const float* __restrict__ ob,
                                               const float* __restrict__ wT2,
                                               const float* __restrict__ off_b,
                                               float* __restrict__ pred) {
    int blk = blockIdx.x;
    int bg = blk / 72, tile = blk % 72;
    int ty0 = (tile / 6) * 8, tx0 = (tile % 6) * 16;
    int b = bg >> 1, g = bg & 1;
    int tid = threadIdx.x;
    __shared__ float ts[180][33];   // 18(w) x 10(h) halo x 32ch (+1 pad)

    if (tid < 180) {
        int hy = ty0 + tid / 18 - 1;
        int hx = tx0 + tid % 18 - 1;
        if (hy < 0 || hy >= OH || hx < 0 || hx >= OW) {
#pragma unroll
            for (int c = 0; c < 32; c++) ts[tid][c] = 0.f;
        } else {
            float vals[32];
#pragma unroll
            for (int c = 0; c < 32; c++) vals[c] = 0.f;
            for (int dy = -1; dy <= 1; dy++) {
                int yy = hy + dy;
                if ((unsigned)yy >= (unsigned)OH) continue;
                for (int dx = -1; dx <= 1; dx++) {
                    int xx = hx + dx;
                    if ((unsigned)xx >= (unsigned)OW) continue;
                    const float4* qp4 = (const float4*)(q_attn +
                        (((size_t)b * N1) + yy * OW + xx) * 64 + g * 32);
                    int wi = (dy + 1) * 3 + (dx + 1);
#pragma unroll
                    for (int c4 = 0; c4 < 8; c4++) {
                        float4 q4 = qp4[c4];
                        vals[c4 * 4 + 0] += q4.x * dw_w[(c4 * 4 + 0) * 9 + wi];
                        vals[c4 * 4 + 1] += q4.y * dw_w[(c4 * 4 + 1) * 9 + wi];
                        vals[c4 * 4 + 2] += q4.z * dw_w[(c4 * 4 + 2) * 9 + wi];
                        vals[c4 * 4 + 3] += q4.w * dw_w[(c4 * 4 + 3) * 9 + wi];
                    }
                }
            }
            float sum = 0.f;
#pragma unroll
            for (int c = 0; c < 32; c++) { vals[c] *= INV_SCALE; sum += vals[c]; }
            float mu = sum * (1.f / 32.f);
            float var = 0.f;
#pragma unroll
            for (int c = 0; c < 32; c++) { float d = vals[c] - mu; var += d * d; }
            float rsv = rsqrtf(var * (1.f / 32.f) + 1e-5f);
#pragma unroll
            for (int c = 0; c < 32; c++) {
                float v = (vals[c] - mu) * rsv * og[c] + ob[c];
                ts[tid][c] = 0.5f * v * (1.f + erff(v * 0.70710678118654752f));
            }
        }
    }
    __syncthreads();

    int och = __builtin_amdgcn_readfirstlane(tid >> 7) * 9;   // wave-uniform
    int pixL = tid & 127;
    int oyl = pixL >> 4, oxl = pixL & 15;
    float acc[9];
#pragma unroll
    for (int o = 0; o < 9; o++) acc[o] = off_b[och + o];
    for (int ic = 0; ic < 32; ic++) {
#pragma unroll
        for (int dy = 0; dy < 3; dy++) {
#pragma unroll
            for (int dx = 0; dx < 3; dx++) {
                float tv = ts[(oyl + dy) * 18 + oxl + dx][ic];
                const float* wr = wT2 + (ic * 9 + dy * 3 + dx) * 18 + och;
#pragma unroll
                for (int o = 0; o < 9; o++) acc[o] += tv * wr[o];
            }
        }
    }
    int p = (ty0 + oyl) * OW + tx0 + oxl;
#pragma unroll
    for (int o = 0; o < 9; o++)
        pred[((size_t)bg * 18 + och + o) * N1 + p] = acc[o];
}

// ---------------- K5: deformable attention, per-wave tap setup hoisted into LDS.
// 1 wave per (bg, pixel); 4 waves/block (same bg, consecutive pixels p..p+3).
__global__ __launch_bounds__(256) void k5_attn(const float* __restrict__ pred,
                                               const float* __restrict__ q_attn,
                                               const float* __restrict__ k_nhwc,
                                               const float* __restrict__ v_nhwc,
                                               const float* __restrict__ rpb,
                                               float* __restrict__ out) {
    int tid = threadIdx.x;
    int wv = tid >> 6, lane = tid & 63;
    int gw = blockIdx.x * 4 + wv;          // 0..36863
    int bg = gw / N1, p = gw % N1;
    int b = bg >> 1, g = bg & 1;
    int oy = p / OW, ox = p % OW;

    __shared__ float4 wts[4][9];    // bilinear corner weights (validity folded in)
    __shared__ int4   koff[4][9];   // corner offsets *32 (k stride)
    __shared__ int4   voff[4][9];   // corner offsets *128 (v stride)
    __shared__ float  ss[4][12];    // raw scores
    __shared__ float  outb[4][128];

    // --- per-wave tap setup (lanes 0-8): weights + clamped offsets once per wave
    if (lane < 9) {
        int j = lane, ky = j / 3, kx = j % 3;
        float py = tanhf(pred[((size_t)bg * 18 + j * 2) * N1 + p]) * 11.0f + (float)(ky - 1) + (float)oy;
        float px = tanhf(pred[((size_t)bg * 18 + j * 2 + 1) * N1 + p]) * 11.0f + (float)(kx - 1) + (float)ox;
        float iy = py * RESZ, ix = px * RESZ;
        float y0f = floorf(iy), x0f = floorf(ix);
        float wy = iy - y0f, wx = ix - x0f;
        int y0 = (int)y0f, x0 = (int)x0f;
        bool vy0 = (unsigned)y0 < 48u, vy1 = (unsigned)(y0 + 1) < 48u;
        bool vx0 = (unsigned)x0 < 48u, vx1 = (unsigned)(x0 + 1) < 48u;
        int y0c = min(max(y0, 0), 47), y1c = min(max(y0 + 1, 0), 47);
        int x0c = min(max(x0, 0), 47), x1c = min(max(x0 + 1, 0), 47);
        float4 w;
        w.x = (vy0 && vx0) ? (1.f - wy) * (1.f - wx) : 0.f;
        w.y = (vy0 && vx1) ? (1.f - wy) * wx : 0.f;
        w.z = (vy1 && vx0) ? wy * (1.f - wx) : 0.f;
        w.w = (vy1 && vx1) ? wy * wx : 0.f;
        wts[wv][j] = w;
        int o00 = y0c * 48 + x0c, o01 = y0c * 48 + x1c;
        int o10 = y1c * 48 + x0c, o11 = y1c * 48 + x1c;
        koff[wv][j] = make_int4(o00 * 32, o01 * 32, o10 * 32, o11 * 32);
        voff[wv][j] = make_int4(o00 * 128, o01 * 128, o10 * 128, o11 * 128);
    }
    __syncthreads();

    // --- scores: lanes (c in [0,32), h in {0,1}) handle 2 taps at a time
    int c = lane & 31, h = lane >> 5;
    float qv = q_attn[((size_t)b * N1 + p) * HID + g * 32 + c];
    const float* kb = k_nhwc + (size_t)bg * HW * 32;

    for (int jj = 0; jj < 5; jj++) {
        int j = jj * 2 + h;
        float partial = 0.f;
        if (j < 9) {
            float4 w = wts[wv][j];
            int4 ko = koff[wv][j];
            float kv = w.x * kb[ko.x + c] + w.y * kb[ko.y + c]
                     + w.z * kb[ko.z + c] + w.w * kb[ko.w + c];
            partial = qv * (kv + rpb[((size_t)g * 9 + j) * 32 + c]);
        }
#pragma unroll
        for (int off = 1; off < 32; off <<= 1) partial += __shfl_xor(partial, off);
        if (c == 0 && j < 9) ss[wv][j] = partial;
    }
    __syncthreads();

    // --- softmax stats (all lanes, static LDS indices)
    float m = -1e30f;
#pragma unroll
    for (int j = 0; j < 9; j++) m = fmaxf(m, ss[wv][j]);
    float sum = 0.f;
#pragma unroll
    for (int j = 0; j < 9; j++) sum += expf(ss[wv][j] - m);
    float inv = 1.f / sum;

    // --- value accumulation: lanes (c4=(lane&31)*4, h) -> float4 over 128 channels
    int c4 = (lane & 31) * 4;
    const float* vb = v_nhwc + (size_t)bg * HW * 128 + c4;
    float4 acc = make_float4(0.f, 0.f, 0.f, 0.f);
    for (int jj = 0; jj < 5; jj++) {
        int j = jj * 2 + h;
        if (j < 9) {
            float pj = expf(ss[wv][j] - m) * inv;
            float4 w = wts[wv][j];
            int4 vo = voff[wv][j];
            float4 a0 = *(const float4*)(vb + vo.x);
            float4 a1 = *(const float4*)(vb + vo.y);
            float4 a2 = *(const float4*)(vb + vo.z);
            float4 a3 = *(const float4*)(vb + vo.w);
            float f0 = w.x * pj, f1 = w.y * pj, f2 = w.z * pj, f3 = w.w * pj;
            acc.x += f0 * a0.x + f1 * a1.x + f2 * a2.x + f3 * a3.x;
            acc.y += f0 * a0.y + f1 * a1.y + f2 * a2.y + f3 * a3.y;
            acc.z += f0 * a0.z + f1 * a1.z + f2 * a2.z + f3 * a3.z;
            acc.w += f0 * a0.w + f1 * a1.w + f2 * a2.w + f3 * a3.w;
        }
    }
    acc.x += __shfl_xor(acc.x, 32);
    acc.y += __shfl_xor(acc.y, 32);
    acc.z += __shfl_xor(acc.z, 32);
    acc.w += __shfl_xor(acc.w, 32);
    if (lane < 32) *(float4*)&outb[wv][c4] = acc;
    __syncthreads();

    // transposed write: thread t<128 writes float4 (4 consecutive pixels) for channel t
    if (tid < 128) {
        int bg0 = (blockIdx.x * 4) / N1;
        int p0 = (blockIdx.x * 4) % N1;
        int b0 = bg0 >> 1, g0 = bg0 & 1;
        float4 v4 = make_float4(outb[0][tid], outb[1][tid], outb[2][tid], outb[3][tid]);
        *(float4*)(out + ((size_t)b0 * NC + g0 * 128 + tid) * N1 + p0) = v4;
    }
}

extern "C" void kernel_launch(void* const* d_in, const int* in_sizes, int n_in,
                              void* d_out, int out_size, void* d_ws, size_t ws_size,
                              hipStream_t stream) {
    const float* x      = (const float*)d_in[0];
    const float* ln_g   = (const float*)d_in[1];
    const float* ln_b   = (const float*)d_in[2];
    const float* Wq     = (const float*)d_in[3];
    const float* Wk     = (const float*)d_in[4];
    const float* dw_w   = (const float*)d_in[5];
    const float* off_g  = (const float*)d_in[6];
    const float* off_bt = (const float*)d_in[7];
    const float* off_w  = (const float*)d_in[8];
    const float* off_b  = (const float*)d_in[9];
    const float* rpb    = (const float*)d_in[10];
    float* out = (float*)d_out;

    // Workspace layout (floats). Total = 3,355,712 floats = 12.80 MB.
    float* ws = (float*)d_ws;
    float* WT     = ws;                       // 32768
    float* k_nhwc = WT + 32768;               // 294912  [4][2304][32]
    float* v_nhwc = k_nhwc + 294912;          // 1179648 [4][2304][128]
    float* q_attn = v_nhwc + 1179648;         // 1179648 [2][9216][64] (scaled)
    float* R      = q_attn + 1179648;         // 663552
    float* q_pix  = R;                        // 294912  [2][2304][64]
    float* pred   = R;                        // 663552  [4][18][9216]
    float* wT2    = R + 663552;               // 5184    [288][18]

    k0_wt<<<149, 256, 0, stream>>>(Wq, Wk, off_w, WT, wT2);
    k1_ln_qk<<<NB * HW, 128, 0, stream>>>(x, ln_g, ln_b, WT, q_pix, k_nhwc);
    k2b_vt<<<1152, 256, 0, stream>>>(x, v_nhwc);
    k2_resize<<<4608, 256, 0, stream>>>(q_pix, q_attn);
    k34_off<<<288, 256, 0, stream>>>(q_attn, dw_w, off_g, off_bt, wT2, off_b, pred);
    k5_attn<<<9216, 256, 0, stream>>>(pred, q_attn, k_nhwc, v_nhwc, rpb, out);
}

// Round 5
// 194.751 us; speedup vs baseline: 1.6658x; 1.0084x over previous
//
#include <hip/hip_runtime.h>
#include <cstdint>
#include <cmath>

// Problem constants
#define NB 2
#define NC 256
#define HW 2304          // 48*48
#define HID 64
#define OH 96
#define OW 96
#define N1 9216          // 96*96
#define SCALE_ATTN 0.17677669529663689f   // 32^-0.5
#define INV_SCALE 5.65685424949238f       // sqrt(32)
#define RESZ ((float)(47.0/95.0))

// ---------------- K0: Wq/Wk -> WT4[c4][128][4] (t<64: Wq row t, else Wk row t-64);
// off_w -> wT2[k=ic*9+tap][18 oc]
__global__ void k0_wt(const float* __restrict__ Wq, const float* __restrict__ Wk,
                      const float* __restrict__ off_w,
                      float* __restrict__ WT4, float* __restrict__ wT2) {
    int idx = blockIdx.x * 256 + threadIdx.x;
    if (idx < 256 * 128) {
        int c = idx >> 7, t = idx & 127;
        float v = (t < 64) ? Wq[t * 256 + c] : Wk[(t - 64) * 256 + c];
        WT4[(((size_t)(c >> 2) * 128) + t) * 4 + (c & 3)] = v;
    } else if (idx < 256 * 128 + 288 * 18) {
        int i = idx - 256 * 128;
        wT2[i] = off_w[(i % 18) * 288 + (i / 18)];
    }
}

// ---------------- K2b: v (=x) NCHW -> NHWC per group via LDS tile: [4][2304][128]
__global__ void k2b_vt(const float* __restrict__ x, float* __restrict__ v_nhwc) {
    int blk = blockIdx.x;
    int pt = blk % 72;
    int t2 = blk / 72;
    int ct = t2 & 3;
    int bg = t2 >> 2;
    int b = bg >> 1, g = bg & 1;
    __shared__ float tile[32][33];
    int tx = threadIdx.x & 31, row = threadIdx.x >> 5;   // row 0..7
#pragma unroll
    for (int r = 0; r < 4; r++) {
        int c = ct * 32 + row + r * 8;
        tile[row + r * 8][tx] = x[((size_t)(b * 256 + g * 128 + c)) * HW + pt * 32 + tx];
    }
    __syncthreads();
#pragma unroll
    for (int r = 0; r < 4; r++) {
        int p = pt * 32 + row + r * 8;
        v_nhwc[((size_t)bg * HW + p) * 128 + ct * 32 + tx] = tile[tx][row + r * 8];
    }
}

// ---------------- K1: channel LN over 256 + Q/K projection, reading coalesced v_nhwc.
// Block = 256 thr = 4 pixels. LN: one wave per pixel, shfl butterfly only.
// Dot: thread (o=tid&127, ph=tid>>7) computes output o for pixels ph*2, ph*2+1.
__global__ __launch_bounds__(256) void k1_ln_qk(const float* __restrict__ v_nhwc,
                         const float* __restrict__ ln_g, const float* __restrict__ ln_b,
                         const float* __restrict__ WT4,
                         float* __restrict__ q_pix, float* __restrict__ k_nhwc) {
    int blk = blockIdx.x;            // 0..1151
    int tid = threadIdx.x;
    int wv = tid >> 6, lane = tid & 63;
    __shared__ float xs[4][256];
    {
        int pix = blk * 4 + wv;
        int b = pix / HW, p = pix % HW;
        int c0 = lane * 2;
        float2 u0 = *(const float2*)(v_nhwc + (((size_t)(b * 2 + 0) * HW) + p) * 128 + c0);
        float2 u1 = *(const float2*)(v_nhwc + (((size_t)(b * 2 + 1) * HW) + p) * 128 + c0);
        float s = u0.x + u0.y + u1.x + u1.y;
#pragma unroll
        for (int off = 1; off < 64; off <<= 1) s += __shfl_xor(s, off);
        float mu = s * (1.f / 256.f);
        float d0 = u0.x - mu, d1 = u0.y - mu, d2 = u1.x - mu, d3 = u1.y - mu;
        float q = d0 * d0 + d1 * d1 + d2 * d2 + d3 * d3;
#pragma unroll
        for (int off = 1; off < 64; off <<= 1) q += __shfl_xor(q, off);
        float rs = rsqrtf(q * (1.f / 256.f) + 1e-5f);
        float2 w0, w1;
        w0.x = d0 * rs * ln_g[c0] + ln_b[c0];
        w0.y = d1 * rs * ln_g[c0 + 1] + ln_b[c0 + 1];
        w1.x = d2 * rs * ln_g[128 + c0] + ln_b[128 + c0];
        w1.y = d3 * rs * ln_g[129 + c0] + ln_b[129 + c0];
        *(float2*)&xs[wv][c0] = w0;
        *(float2*)&xs[wv][128 + c0] = w1;
    }
    __syncthreads();
    int o = tid & 127, ph = tid >> 7;
    float a0 = 0.f, a1 = 0.f;
    const float4* wp = (const float4*)WT4 + o;         // stride 128 float4s per c4
    const float4* xa = (const float4*)xs[ph * 2];
    const float4* xb = (const float4*)xs[ph * 2 + 1];
#pragma unroll 8
    for (int c4 = 0; c4 < 64; c4++) {
        float4 w = wp[(size_t)c4 * 128];
        float4 p0 = xa[c4], p1 = xb[c4];
        a0 += w.x * p0.x + w.y * p0.y + w.z * p0.z + w.w * p0.w;
        a1 += w.x * p1.x + w.y * p1.y + w.z * p1.z + w.w * p1.w;
    }
#pragma unroll
    for (int k = 0; k < 2; k++) {
        int pix = blk * 4 + ph * 2 + k;
        int b = pix / HW, p = pix % HW;
        float a = k ? a1 : a0;
        if (o < 64) {
            q_pix[(((size_t)b * HW) + p) * 64 + o] = a;
        } else {
            int t = o - 64, g = t >> 5, c32 = t & 31;
            k_nhwc[(((size_t)(b * 2 + g) * HW) + p) * 32 + c32] = a;
        }
    }
}

// ---------------- K2: bilinear resize q 48->96 (align_corners), pixel-major in and out.
__global__ void k2_resize(const float* __restrict__ q_pix, float* __restrict__ q_attn) {
    int idx = blockIdx.x * 256 + threadIdx.x;   // 2*9216*64
    if (idx >= NB * N1 * HID) return;
    int c = idx & 63;
    int t = idx >> 6;
    int p = t % N1;
    int b = t / N1;
    int oy = p / OW, ox = p % OW;
    float ys = oy * RESZ, xsf = ox * RESZ;
    int y0 = (int)floorf(ys); y0 = min(max(y0, 0), 46); float wy = ys - (float)y0;
    int x0 = (int)floorf(xsf); x0 = min(max(x0, 0), 46); float wx = xsf - (float)x0;
    const float* base = q_pix + (size_t)b * HW * 64 + c;
    float a00 = base[(y0 * 48 + x0) * 64],       a01 = base[(y0 * 48 + x0 + 1) * 64];
    float a10 = base[((y0 + 1) * 48 + x0) * 64], a11 = base[((y0 + 1) * 48 + x0 + 1) * 64];
    float v = (a00 * (1.f - wy) + a10 * wy) * (1.f - wx) + (a01 * (1.f - wy) + a11 * wy) * wx;
    q_attn[idx] = v * SCALE_ATTN;
}

// ---------------- K34: fused depthwise3x3 + LN(32) + GELU + conv3x3(32->18)+bias.
__global__ __launch_bounds__(256) void k34_off(const float* __restrict__ q_attn,
                                               const float* __restrict__ dw_w,
                                               const float* __restrict__ og,
                                               const float* __restrict__ ob,
                                               const float* __restrict__ wT2,
                                               const float* __restrict__ off_b,
                                               float* __restrict__ pred) {
    int blk = blockIdx.x;
    int bg = blk / 72, tile = blk % 72;
    int ty0 = (tile / 6) * 8, tx0 = (tile % 6) * 16;
    int b = bg >> 1, g = bg & 1;
    int tid = threadIdx.x;
    __shared__ float ts[180][33];   // 18(w) x 10(h) halo x 32ch (+1 pad)

    if (tid < 180) {
        int hy = ty0 + tid / 18 - 1;
        int hx = tx0 + tid % 18 - 1;
        if (hy < 0 || hy >= OH || hx < 0 || hx >= OW) {
#pragma unroll
            for (int c = 0; c < 32; c++) ts[tid][c] = 0.f;
        } else {
            float vals[32];
#pragma unroll
            for (int c = 0; c < 32; c++) vals[c] = 0.f;
            for (int dy = -1; dy <= 1; dy++) {
                int yy = hy + dy;
                if ((unsigned)yy >= (unsigned)OH) continue;
                for (int dx = -1; dx <= 1; dx++) {
                    int xx = hx + dx;
                    if ((unsigned)xx >= (unsigned)OW) continue;
                    const float4* qp4 = (const float4*)(q_attn +
                        (((size_t)b * N1) + yy * OW + xx) * 64 + g * 32);
                    int wi = (dy + 1) * 3 + (dx + 1);
#pragma unroll
                    for (int c4 = 0; c4 < 8; c4++) {
                        float4 q4 = qp4[c4];
                        vals[c4 * 4 + 0] += q4.x * dw_w[(c4 * 4 + 0) * 9 + wi];
                        vals[c4 * 4 + 1] += q4.y * dw_w[(c4 * 4 + 1) * 9 + wi];
                        vals[c4 * 4 + 2] += q4.z * dw_w[(c4 * 4 + 2) * 9 + wi];
                        vals[c4 * 4 + 3] += q4.w * dw_w[(c4 * 4 + 3) * 9 + wi];
                    }
                }
            }
            float sum = 0.f;
#pragma unroll
            for (int c = 0; c < 32; c++) { vals[c] *= INV_SCALE; sum += vals[c]; }
            float mu = sum * (1.f / 32.f);
            float var = 0.f;
#pragma unroll
            for (int c = 0; c < 32; c++) { float d = vals[c] - mu; var += d * d; }
            float rsv = rsqrtf(var * (1.f / 32.f) + 1e-5f);
#pragma unroll
            for (int c = 0; c < 32; c++) {
                float v = (vals[c] - mu) * rsv * og[c] + ob[c];
                ts[tid][c] = 0.5f * v * (1.f + erff(v * 0.70710678118654752f));
            }
        }
    }
    __syncthreads();

    int och = __builtin_amdgcn_readfirstlane(tid >> 7) * 9;   // wave-uniform
    int pixL = tid & 127;
    int oyl = pixL >> 4, oxl = pixL & 15;
    float acc[9];
#pragma unroll
    for (int o = 0; o < 9; o++) acc[o] = off_b[och + o];
    for (int ic = 0; ic < 32; ic++) {
#pragma unroll
        for (int dy = 0; dy < 3; dy++) {
#pragma unroll
            for (int dx = 0; dx < 3; dx++) {
                float tv = ts[(oyl + dy) * 18 + oxl + dx][ic];
                const float* wr = wT2 + (ic * 9 + dy * 3 + dx) * 18 + och;
#pragma unroll
                for (int o = 0; o < 9; o++) acc[o] += tv * wr[o];
            }
        }
    }
    int p = (ty0 + oyl) * OW + tx0 + oxl;
#pragma unroll
    for (int o = 0; o < 9; o++)
        pred[((size_t)bg * 18 + och + o) * N1 + p] = acc[o];
}

// ---------------- K5: deformable attention.
// 1 wave per (bg, pixel); softmax folded into per-tap corner weights once per wave;
// v-phase tap-serial with wave-uniform scalar corner bases, float2 per lane.
__global__ __launch_bounds__(256) void k5_attn(const float* __restrict__ pred,
                                               const float* __restrict__ q_attn,
                                               const float* __restrict__ k_nhwc,
                                               const float* __restrict__ v_nhwc,
                                               const float* __restrict__ rpb,
                                               float* __restrict__ out) {
    int tid = threadIdx.x;
    int wv = __builtin_amdgcn_readfirstlane(tid >> 6);   // wave-uniform
    int lane = tid & 63;
    int gw = blockIdx.x * 4 + wv;          // 0..36863 (scalar)
    int bg = gw / N1, p = gw % N1;
    int b = bg >> 1, g = bg & 1;
    int oy = p / OW, ox = p % OW;

    __shared__ float4 wts[4][9];    // bilinear corner weights (validity folded in)
    __shared__ float4 wp4[4][9];    // corner weights * softmax prob
    __shared__ int4   cof[4][9];    // corner pixel offsets (unscaled, clamped)
    __shared__ float  ss[4][12];    // raw scores
    __shared__ float  outb[4][128];

    // --- per-wave tap setup (lanes 0-8)
    if (lane < 9) {
        int j = lane, ky = j / 3, kx = j % 3;
        float pr0 = pred[((size_t)bg * 18 + j * 2) * N1 + p];
        float pr1 = pred[((size_t)bg * 18 + j * 2 + 1) * N1 + p];
        float th0 = 1.f - 2.f * __builtin_amdgcn_rcpf(__expf(2.f * pr0) + 1.f);
        float th1 = 1.f - 2.f * __builtin_amdgcn_rcpf(__expf(2.f * pr1) + 1.f);
        float py = th0 * 11.0f + (float)(ky - 1) + (float)oy;
        float px = th1 * 11.0f + (float)(kx - 1) + (float)ox;
        float iy = py * RESZ, ix = px * RESZ;
        float y0f = floorf(iy), x0f = floorf(ix);
        float wy = iy - y0f, wx = ix - x0f;
        int y0 = (int)y0f, x0 = (int)x0f;
        bool vy0 = (unsigned)y0 < 48u, vy1 = (unsigned)(y0 + 1) < 48u;
        bool vx0 = (unsigned)x0 < 48u, vx1 = (unsigned)(x0 + 1) < 48u;
        int y0c = min(max(y0, 0), 47), y1c = min(max(y0 + 1, 0), 47);
        int x0c = min(max(x0, 0), 47), x1c = min(max(x0 + 1, 0), 47);
        float4 w;
        w.x = (vy0 && vx0) ? (1.f - wy) * (1.f - wx) : 0.f;
        w.y = (vy0 && vx1) ? (1.f - wy) * wx : 0.f;
        w.z = (vy1 && vx0) ? wy * (1.f - wx) : 0.f;
        w.w = (vy1 && vx1) ? wy * wx : 0.f;
        wts[wv][j] = w;
        cof[wv][j] = make_int4(y0c * 48 + x0c, y0c * 48 + x1c,
                               y1c * 48 + x0c, y1c * 48 + x1c);
    }
    __syncthreads();

    // --- scores: lanes (c in [0,32), h in {0,1}) handle 2 taps at a time
    int c = lane & 31, h = lane >> 5;
    float qv = q_attn[((size_t)b * N1 + p) * HID + g * 32 + c];
    const float* kb = k_nhwc + (size_t)bg * HW * 32;
    const float* rb = rpb + (size_t)g * 288;

    for (int jj = 0; jj < 5; jj++) {
        int j = jj * 2 + h;
        float partial = 0.f;
        if (j < 9) {
            float4 w = wts[wv][j];
            int4 co = cof[wv][j];
            float kv = w.x * kb[co.x * 32 + c] + w.y * kb[co.y * 32 + c]
                     + w.z * kb[co.z * 32 + c] + w.w * kb[co.w * 32 + c];
            partial = qv * (kv + rb[j * 32 + c]);
        }
#pragma unroll
        for (int off = 1; off < 32; off <<= 1) partial += __shfl_xor(partial, off);
        if (c == 0 && j < 9) ss[wv][j] = partial;
    }
    __syncthreads();

    // --- softmax once per wave (lanes 0-15), folded into corner weights
    {
        float sv = (lane < 9) ? ss[wv][lane] : -1e30f;
        float m = sv;
#pragma unroll
        for (int off = 1; off < 16; off <<= 1) m = fmaxf(m, __shfl_xor(m, off));
        float e = (lane < 9) ? __expf(sv - m) : 0.f;
        float t = e;
#pragma unroll
        for (int off = 1; off < 16; off <<= 1) t += __shfl_xor(t, off);
        float pj = e * __builtin_amdgcn_rcpf(t);
        if (lane < 9) {
            float4 w = wts[wv][lane];
            wp4[wv][lane] = make_float4(w.x * pj, w.y * pj, w.z * pj, w.w * pj);
        }
    }
    __syncthreads();

    // --- value phase: tap-serial, scalar corner bases, float2/lane over 128 ch
    const float* vbase = v_nhwc + (size_t)bg * HW * 128;
    int cl2 = lane * 2;
    float ax = 0.f, ay = 0.f;
#pragma unroll
    for (int j = 0; j < 9; j++) {
        float4 w = wp4[wv][j];
        int4 co = cof[wv][j];
        const float* c0p = vbase + (size_t)__builtin_amdgcn_readfirstlane(co.x) * 128;
        const float* c1p = vbase + (size_t)__builtin_amdgcn_readfirstlane(co.y) * 128;
        const float* c2p = vbase + (size_t)__builtin_amdgcn_readfirstlane(co.z) * 128;
        const float* c3p = vbase + (size_t)__builtin_amdgcn_readfirstlane(co.w) * 128;
        float2 a0 = *(const float2*)(c0p + cl2);
        float2 a1 = *(const float2*)(c1p + cl2);
        float2 a2 = *(const float2*)(c2p + cl2);
        float2 a3 = *(const float2*)(c3p + cl2);
        ax += w.x * a0.x + w.y * a1.x + w.z * a2.x + w.w * a3.x;
        ay += w.x * a0.y + w.y * a1.y + w.z * a2.y + w.w * a3.y;
    }
    outb[wv][cl2] = ax;
    outb[wv][cl2 + 1] = ay;
    __syncthreads();

    // transposed write: thread t<128 writes float4 (4 consecutive pixels) for channel t
    if (tid < 128) {
        int bg0 = (blockIdx.x * 4) / N1;
        int p0 = (blockIdx.x * 4) % N1;
        int b0 = bg0 >> 1, g0 = bg0 & 1;
        float4 v4 = make_float4(outb[0][tid], outb[1][tid], outb[2][tid], outb[3][tid]);
        *(float4*)(out + ((size_t)b0 * NC + g0 * 128 + tid) * N1 + p0) = v4;
    }
}

extern "C" void kernel_launch(void* const* d_in, const int* in_sizes, int n_in,
                              void* d_out, int out_size, void* d_ws, size_t ws_size,
                              hipStream_t stream) {
    const float* x      = (const float*)d_in[0];
    const float* ln_g   = (const float*)d_in[1];
    const float* ln_b   = (const float*)d_in[2];
    const float* Wq     = (const float*)d_in[3];
    const float* Wk     = (const float*)d_in[4];
    const float* dw_w   = (const float*)d_in[5];
    const float* off_g  = (const float*)d_in[6];
    const float* off_bt = (const float*)d_in[7];
    const float* off_w  = (const float*)d_in[8];
    const float* off_b  = (const float*)d_in[9];
    const float* rpb    = (const float*)d_in[10];
    float* out = (float*)d_out;

    // Workspace layout (floats). Total = 3,355,712 floats = 12.80 MB.
    float* ws = (float*)d_ws;
    float* WT4    = ws;                       // 32768  [64][128][4]
    float* k_nhwc = WT4 + 32768;              // 294912  [4][2304][32]
    float* v_nhwc = k_nhwc + 294912;          // 1179648 [4][2304][128]
    float* q_attn = v_nhwc + 1179648;         // 1179648 [2][9216][64] (scaled)
    float* R      = q_attn + 1179648;         // 663552
    float* q_pix  = R;                        // 294912  [2][2304][64]
    float* pred   = R;                        // 663552  [4][18][9216]
    float* wT2    = R + 663552;               // 5184    [288][18]

    k0_wt<<<149, 256, 0, stream>>>(Wq, Wk, off_w, WT4, wT2);
    k2b_vt<<<1152, 256, 0, stream>>>(x, v_nhwc);
    k1_ln_qk<<<1152, 256, 0, stream>>>(v_nhwc, ln_g, ln_b, WT4, q_pix, k_nhwc);
    k2_resize<<<4608, 256, 0, stream>>>(q_pix, q_attn);
    k34_off<<<288, 256, 0, stream>>>(q_attn, dw_w, off_g, off_bt, wT2, off_b, pred);
    k5_attn<<<9216, 256, 0, stream>>>(pred, q_attn, k_nhwc, v_nhwc, rpb, out);
}

// Round 6
// 187.357 us; speedup vs baseline: 1.7315x; 1.0395x over previous
//
#include <hip/hip_runtime.h>
#include <cstdint>
#include <cmath>

// Problem constants
#define NB 2
#define NC 256
#define HW 2304          // 48*48
#define HID 64
#define OH 96
#define OW 96
#define N1 9216          // 96*96
#define SCALE_ATTN 0.17677669529663689f   // 32^-0.5
#define RESZ ((float)(47.0/95.0))

// ---------------- KA: fused prep. blk<1152: x NCHW -> v_nhwc [4][2304][128];
// else: Wq/Wk -> WT4[c4][128][4], off_w -> wT2[k=ic*9+tap][18]
__global__ void kA_prep(const float* __restrict__ x, const float* __restrict__ Wq,
                        const float* __restrict__ Wk, const float* __restrict__ off_w,
                        float* __restrict__ v_nhwc, float* __restrict__ WT4,
                        float* __restrict__ wT2) {
    int blk = blockIdx.x;
    if (blk < 1152) {
        int pt = blk % 72;
        int t2 = blk / 72;
        int ct = t2 & 3;
        int bg = t2 >> 2;
        int b = bg >> 1, g = bg & 1;
        __shared__ float tile[32][33];
        int tx = threadIdx.x & 31, row = threadIdx.x >> 5;   // row 0..7
#pragma unroll
        for (int r = 0; r < 4; r++) {
            int c = ct * 32 + row + r * 8;
            tile[row + r * 8][tx] = x[((size_t)(b * 256 + g * 128 + c)) * HW + pt * 32 + tx];
        }
        __syncthreads();
#pragma unroll
        for (int r = 0; r < 4; r++) {
            int p = pt * 32 + row + r * 8;
            v_nhwc[((size_t)bg * HW + p) * 128 + ct * 32 + tx] = tile[tx][row + r * 8];
        }
    } else {
        int idx = (blk - 1152) * 256 + threadIdx.x;
        if (idx < 256 * 128) {
            int c = idx >> 7, t = idx & 127;
            float v = (t < 64) ? Wq[t * 256 + c] : Wk[(t - 64) * 256 + c];
            WT4[(((size_t)(c >> 2) * 128) + t) * 4 + (c & 3)] = v;
        } else if (idx < 256 * 128 + 288 * 18) {
            int i = idx - 256 * 128;
            wT2[i] = off_w[(i % 18) * 288 + (i / 18)];
        }
    }
}

// ---------------- K1: channel LN over 256 + Q/K projection, reading coalesced v_nhwc.
__global__ __launch_bounds__(256) void k1_ln_qk(const float* __restrict__ v_nhwc,
                         const float* __restrict__ ln_g, const float* __restrict__ ln_b,
                         const float* __restrict__ WT4,
                         float* __restrict__ q_pix, float* __restrict__ k_nhwc) {
    int blk = blockIdx.x;            // 0..1151
    int tid = threadIdx.x;
    int wv = tid >> 6, lane = tid & 63;
    __shared__ float xs[4][256];
    {
        int pix = blk * 4 + wv;
        int b = pix / HW, p = pix % HW;
        int c0 = lane * 2;
        float2 u0 = *(const float2*)(v_nhwc + (((size_t)(b * 2 + 0) * HW) + p) * 128 + c0);
        float2 u1 = *(const float2*)(v_nhwc + (((size_t)(b * 2 + 1) * HW) + p) * 128 + c0);
        float s = u0.x + u0.y + u1.x + u1.y;
#pragma unroll
        for (int off = 1; off < 64; off <<= 1) s += __shfl_xor(s, off);
        float mu = s * (1.f / 256.f);
        float d0 = u0.x - mu, d1 = u0.y - mu, d2 = u1.x - mu, d3 = u1.y - mu;
        float q = d0 * d0 + d1 * d1 + d2 * d2 + d3 * d3;
#pragma unroll
        for (int off = 1; off < 64; off <<= 1) q += __shfl_xor(q, off);
        float rs = rsqrtf(q * (1.f / 256.f) + 1e-5f);
        float2 w0, w1;
        w0.x = d0 * rs * ln_g[c0] + ln_b[c0];
        w0.y = d1 * rs * ln_g[c0 + 1] + ln_b[c0 + 1];
        w1.x = d2 * rs * ln_g[128 + c0] + ln_b[128 + c0];
        w1.y = d3 * rs * ln_g[129 + c0] + ln_b[129 + c0];
        *(float2*)&xs[wv][c0] = w0;
        *(float2*)&xs[wv][128 + c0] = w1;
    }
    __syncthreads();
    int o = tid & 127, ph = tid >> 7;
    float a0 = 0.f, a1 = 0.f;
    const float4* wp = (const float4*)WT4 + o;         // stride 128 float4s per c4
    const float4* xa = (const float4*)xs[ph * 2];
    const float4* xb = (const float4*)xs[ph * 2 + 1];
#pragma unroll 8
    for (int c4 = 0; c4 < 64; c4++) {
        float4 w = wp[(size_t)c4 * 128];
        float4 p0 = xa[c4], p1 = xb[c4];
        a0 += w.x * p0.x + w.y * p0.y + w.z * p0.z + w.w * p0.w;
        a1 += w.x * p1.x + w.y * p1.y + w.z * p1.z + w.w * p1.w;
    }
#pragma unroll
    for (int k = 0; k < 2; k++) {
        int pix = blk * 4 + ph * 2 + k;
        int b = pix / HW, p = pix % HW;
        float a = k ? a1 : a0;
        if (o < 64) {
            q_pix[(((size_t)b * HW) + p) * 64 + o] = a;
        } else {
            int t = o - 64, g = t >> 5, c32 = t & 31;
            k_nhwc[(((size_t)(b * 2 + g) * HW) + p) * 32 + c32] = a;
        }
    }
}

// ---------------- K34: fused [resize-on-the-fly] depthwise3x3 + LN(32) + GELU
//                  + conv3x3(32->18)+bias.
__global__ __launch_bounds__(256) void k34_off(const float* __restrict__ q_pix,
                                               const float* __restrict__ dw_w,
                                               const float* __restrict__ og,
                                               const float* __restrict__ ob,
                                               const float* __restrict__ wT2,
                                               const float* __restrict__ off_b,
                                               float* __restrict__ pred) {
    int blk = blockIdx.x;
    int bg = blk / 72, tile = blk % 72;
    int ty0 = (tile / 6) * 8, tx0 = (tile % 6) * 16;
    int b = bg >> 1, g = bg & 1;
    int tid = threadIdx.x;
    __shared__ float ts[180][33];   // 18(w) x 10(h) halo x 32ch (+1 pad)

    if (tid < 180) {
        int hy = ty0 + tid / 18 - 1;
        int hx = tx0 + tid % 18 - 1;
        if (hy < 0 || hy >= OH || hx < 0 || hx >= OW) {
#pragma unroll
            for (int c = 0; c < 32; c++) ts[tid][c] = 0.f;
        } else {
            const float* qb = q_pix + (size_t)b * HW * 64 + g * 32;
            float vals[32];
#pragma unroll
            for (int c = 0; c < 32; c++) vals[c] = 0.f;
            for (int dy = -1; dy <= 1; dy++) {
                int yy = hy + dy;
                if ((unsigned)yy >= (unsigned)OH) continue;
                float ysf = yy * RESZ;
                int y0 = min((int)ysf, 46);
                float wy = ysf - (float)y0;
                for (int dx = -1; dx <= 1; dx++) {
                    int xx = hx + dx;
                    if ((unsigned)xx >= (unsigned)OW) continue;
                    float xsf = xx * RESZ;
                    int x0 = min((int)xsf, 46);
                    float wx = xsf - (float)x0;
                    int i00 = (y0 * 48 + x0) * 64;
                    const float4* q00 = (const float4*)(qb + i00);
                    const float4* q01 = (const float4*)(qb + i00 + 64);
                    const float4* q10 = (const float4*)(qb + i00 + 48 * 64);
                    const float4* q11 = (const float4*)(qb + i00 + 49 * 64);
                    float w00 = (1.f - wy) * (1.f - wx), w01 = (1.f - wy) * wx;
                    float w10 = wy * (1.f - wx),         w11 = wy * wx;
                    int wi = (dy + 1) * 3 + (dx + 1);
#pragma unroll
                    for (int c4 = 0; c4 < 8; c4++) {
                        float4 a = q00[c4], bq = q01[c4], cq = q10[c4], dq = q11[c4];
                        float qx = w00 * a.x + w01 * bq.x + w10 * cq.x + w11 * dq.x;
                        float qy = w00 * a.y + w01 * bq.y + w10 * cq.y + w11 * dq.y;
                        float qz = w00 * a.z + w01 * bq.z + w10 * cq.z + w11 * dq.z;
                        float qw = w00 * a.w + w01 * bq.w + w10 * cq.w + w11 * dq.w;
                        vals[c4 * 4 + 0] += qx * dw_w[(c4 * 4 + 0) * 9 + wi];
                        vals[c4 * 4 + 1] += qy * dw_w[(c4 * 4 + 1) * 9 + wi];
                        vals[c4 * 4 + 2] += qz * dw_w[(c4 * 4 + 2) * 9 + wi];
                        vals[c4 * 4 + 3] += qw * dw_w[(c4 * 4 + 3) * 9 + wi];
                    }
                }
            }
            float sum = 0.f;
#pragma unroll
            for (int c = 0; c < 32; c++) sum += vals[c];
            float mu = sum * (1.f / 32.f);
            float var = 0.f;
#pragma unroll
            for (int c = 0; c < 32; c++) { float d = vals[c] - mu; var += d * d; }
            float rsv = rsqrtf(var * (1.f / 32.f) + 1e-5f);
#pragma unroll
            for (int c = 0; c < 32; c++) {
                float v = (vals[c] - mu) * rsv * og[c] + ob[c];
                ts[tid][c] = 0.5f * v * (1.f + erff(v * 0.70710678118654752f));
            }
        }
    }
    __syncthreads();

    int och = __builtin_amdgcn_readfirstlane(tid >> 7) * 9;   // wave-uniform
    int pixL = tid & 127;
    int oyl = pixL >> 4, oxl = pixL & 15;
    float acc[9];
#pragma unroll
    for (int o = 0; o < 9; o++) acc[o] = off_b[och + o];
    for (int ic = 0; ic < 32; ic++) {
#pragma unroll
        for (int dy = 0; dy < 3; dy++) {
#pragma unroll
            for (int dx = 0; dx < 3; dx++) {
                float tv = ts[(oyl + dy) * 18 + oxl + dx][ic];
                const float* wr = wT2 + (ic * 9 + dy * 3 + dx) * 18 + och;
#pragma unroll
                for (int o = 0; o < 9; o++) acc[o] += tv * wr[o];
            }
        }
    }
    int p = (ty0 + oyl) * OW + tx0 + oxl;
#pragma unroll
    for (int o = 0; o < 9; o++)
        pred[((size_t)bg * 18 + och + o) * N1 + p] = acc[o];
}

// ---------------- K5: deformable attention. 1 wave = 4 consecutive pixels (same row);
// block = 16 pixels. q resized on the fly; softmax fully in-register; v-phase with
// per-lane float4 vector addressing (h-split over taps) + shfl combine.
__global__ __launch_bounds__(256) void k5_attn(const float* __restrict__ pred,
                                               const float* __restrict__ q_pix,
                                               const float* __restrict__ k_nhwc,
                                               const float* __restrict__ v_nhwc,
                                               const float* __restrict__ rpb,
                                               float* __restrict__ out) {
    int tid = threadIdx.x;
    int wv = __builtin_amdgcn_readfirstlane(tid >> 6);
    int lane = tid & 63;
    int gp = blockIdx.x * 16;              // block-base pixel (same bg, same row)
    int bg = gp / N1, p0 = gp % N1;
    int b = bg >> 1, g = bg & 1;
    int pw = p0 + wv * 4;                  // wave-base pixel
    int oy = pw / OW, ox0 = pw % OW;

    __shared__ float4 wts[4][4][9];        // [wave][px][tap] corner weights
    __shared__ int4   cof[4][4][9];        // [wave][px][tap] corner pixel offsets
    __shared__ float  outb[4][4][128];     // [wave][px][ch]

    // --- tap setup: lanes 0..35 -> (px, j)
    if (lane < 36) {
        int px = lane / 9, j = lane % 9;
        int p = pw + px;
        int ky = j / 3, kx = j % 3;
        float pr0 = pred[((size_t)bg * 18 + j * 2) * N1 + p];
        float pr1 = pred[((size_t)bg * 18 + j * 2 + 1) * N1 + p];
        float th0 = 1.f - 2.f * __builtin_amdgcn_rcpf(__expf(2.f * pr0) + 1.f);
        float th1 = 1.f - 2.f * __builtin_amdgcn_rcpf(__expf(2.f * pr1) + 1.f);
        float py  = th0 * 11.0f + (float)(ky - 1) + (float)oy;
        float pxc = th1 * 11.0f + (float)(kx - 1) + (float)(ox0 + px);
        float iy = py * RESZ, ix = pxc * RESZ;
        float y0f = floorf(iy), x0f = floorf(ix);
        float wy = iy - y0f, wx = ix - x0f;
        int y0 = (int)y0f, x0 = (int)x0f;
        bool vy0 = (unsigned)y0 < 48u, vy1 = (unsigned)(y0 + 1) < 48u;
        bool vx0 = (unsigned)x0 < 48u, vx1 = (unsigned)(x0 + 1) < 48u;
        int y0c = min(max(y0, 0), 47), y1c = min(max(y0 + 1, 0), 47);
        int x0c = min(max(x0, 0), 47), x1c = min(max(x0 + 1, 0), 47);
        float4 w;
        w.x = (vy0 && vx0) ? (1.f - wy) * (1.f - wx) : 0.f;
        w.y = (vy0 && vx1) ? (1.f - wy) * wx : 0.f;
        w.z = (vy1 && vx0) ? wy * (1.f - wx) : 0.f;
        w.w = (vy1 && vx1) ? wy * wx : 0.f;
        wts[wv][px][j] = w;
        cof[wv][px][j] = make_int4(y0c * 48 + x0c, y0c * 48 + x1c,
                                   y1c * 48 + x0c, y1c * 48 + x1c);
    }
    __syncthreads();

    int c = lane & 31, h = lane >> 5;
    int c4 = (lane & 31) * 4;
    const float* kb = k_nhwc + (size_t)bg * HW * 32;
    const float* rb = rpb + (size_t)g * 288;
    const float* qb = q_pix + (size_t)b * HW * 64 + g * 32 + c;
    const float* vbase = v_nhwc + (size_t)bg * HW * 128;

    float ysf = oy * RESZ;
    int qy0 = min((int)ysf, 46);
    float qwy = ysf - (float)qy0;

    for (int px = 0; px < 4; px++) {
        // on-the-fly resized q (lane c channel)
        float xsf = (ox0 + px) * RESZ;
        int qx0 = min((int)xsf, 46);
        float qwx = xsf - (float)qx0;
        int qi = (qy0 * 48 + qx0) * 64;
        float q00 = qb[qi], q01 = qb[qi + 64];
        float q10 = qb[qi + 48 * 64], q11 = qb[qi + 49 * 64];
        float qv = ((q00 * (1.f - qwy) + q10 * qwy) * (1.f - qwx)
                  + (q01 * (1.f - qwy) + q11 * qwy) * qwx) * SCALE_ATTN;

        // scores: h-split taps; after xor-reduce all 32 lanes of a half hold the sum
        float s[5], e[5];
#pragma unroll
        for (int jj = 0; jj < 5; jj++) {
            int j = jj * 2 + h;
            float partial = 0.f;
            if (j < 9) {
                float4 w = wts[wv][px][j];
                int4 co = cof[wv][px][j];
                float kv = w.x * kb[co.x * 32 + c] + w.y * kb[co.y * 32 + c]
                         + w.z * kb[co.z * 32 + c] + w.w * kb[co.w * 32 + c];
                partial = qv * (kv + rb[j * 32 + c]);
            }
#pragma unroll
            for (int off = 1; off < 32; off <<= 1) partial += __shfl_xor(partial, off);
            s[jj] = (j < 9) ? partial : -1e30f;
        }
        // in-register softmax across both halves
        float m = s[0];
#pragma unroll
        for (int jj = 1; jj < 5; jj++) m = fmaxf(m, s[jj]);
        m = fmaxf(m, __shfl_xor(m, 32));
        float sum = 0.f;
#pragma unroll
        for (int jj = 0; jj < 5; jj++) { e[jj] = __expf(s[jj] - m); sum += e[jj]; }
        sum += __shfl_xor(sum, 32);
        float inv = __builtin_amdgcn_rcpf(sum);

        // value phase: float4 per lane over 128 ch, h-split taps
        float4 acc = make_float4(0.f, 0.f, 0.f, 0.f);
#pragma unroll
        for (int jj = 0; jj < 5; jj++) {
            int j = jj * 2 + h;
            if (j < 9) {
                float pj = e[jj] * inv;
                float4 w = wts[wv][px][j];
                int4 co = cof[wv][px][j];
                float4 a0 = *(const float4*)(vbase + (size_t)co.x * 128 + c4);
                float4 a1 = *(const float4*)(vbase + (size_t)co.y * 128 + c4);
                float4 a2 = *(const float4*)(vbase + (size_t)co.z * 128 + c4);
                float4 a3 = *(const float4*)(vbase + (size_t)co.w * 128 + c4);
                float f0 = w.x * pj, f1 = w.y * pj, f2 = w.z * pj, f3 = w.w * pj;
                acc.x += f0 * a0.x + f1 * a1.x + f2 * a2.x + f3 * a3.x;
                acc.y += f0 * a0.y + f1 * a1.y + f2 * a2.y + f3 * a3.y;
                acc.z += f0 * a0.z + f1 * a1.z + f2 * a2.z + f3 * a3.z;
                acc.w += f0 * a0.w + f1 * a1.w + f2 * a2.w + f3 * a3.w;
            }
        }
        acc.x += __shfl_xor(acc.x, 32);
        acc.y += __shfl_xor(acc.y, 32);
        acc.z += __shfl_xor(acc.z, 32);
        acc.w += __shfl_xor(acc.w, 32);
        if (lane < 32) *(float4*)&outb[wv][px][c4] = acc;
    }
    __syncthreads();

    // final write: thread ch<128 writes 4x float4 = 64B contiguous per channel
    if (tid < 128) {
        int ch = tid;
        float* op = out + ((size_t)b * NC + g * 128 + ch) * N1 + p0;
#pragma unroll
        for (int w2 = 0; w2 < 4; w2++) {
            float4 v4 = make_float4(outb[w2][0][ch], outb[w2][1][ch],
                                    outb[w2][2][ch], outb[w2][3][ch]);
            *(float4*)(op + w2 * 4) = v4;
        }
    }
}

extern "C" void kernel_launch(void* const* d_in, const int* in_sizes, int n_in,
                              void* d_out, int out_size, void* d_ws, size_t ws_size,
                              hipStream_t stream) {
    const float* x      = (const float*)d_in[0];
    const float* ln_g   = (const float*)d_in[1];
    const float* ln_b   = (const float*)d_in[2];
    const float* Wq     = (const float*)d_in[3];
    const float* Wk     = (const float*)d_in[4];
    const float* dw_w   = (const float*)d_in[5];
    const float* off_g  = (const float*)d_in[6];
    const float* off_bt = (const float*)d_in[7];
    const float* off_w  = (const float*)d_in[8];
    const float* off_b  = (const float*)d_in[9];
    const float* rpb    = (const float*)d_in[10];
    float* out = (float*)d_out;

    // Workspace layout (floats). Total = 2,470,976 floats = 9.43 MB. No aliasing.
    float* ws = (float*)d_ws;
    float* WT4    = ws;                       // 32768   [64][128][4]
    float* k_nhwc = WT4 + 32768;              // 294912  [4][2304][32]
    float* v_nhwc = k_nhwc + 294912;          // 1179648 [4][2304][128]
    float* q_pix  = v_nhwc + 1179648;         // 294912  [2][2304][64]
    float* pred   = q_pix + 294912;           // 663552  [4][18][9216]
    float* wT2    = pred + 663552;            // 5184    [288][18]

    kA_prep<<<1301, 256, 0, stream>>>(x, Wq, Wk, off_w, v_nhwc, WT4, wT2);
    k1_ln_qk<<<1152, 256, 0, stream>>>(v_nhwc, ln_g, ln_b, WT4, q_pix, k_nhwc);
    k34_off<<<288, 256, 0, stream>>>(q_pix, dw_w, off_g, off_bt, wT2, off_b, pred);
    k5_attn<<<2304, 256, 0, stream>>>(pred, q_pix, k_nhwc, v_nhwc, rpb, out);
}